// Round 5
// baseline (208.798 us; speedup 1.0000x reference)
//
#include <hip/hip_runtime.h>
#include <stdint.h>

#define N_NODES 50000
#define N_EDGES 600000
#define DIM 128

// ---- workspace layout (bytes) ----
#define WS_CNT     0            // 50000 * 4
#define WS_OFF     204800       // 50001 * 4
#define WS_CUR     409600       // 50000 * 4
#define WS_CSR     614400       // 600000 * 4
#define WS_BFRAG   3014656      // 2 * 16384 shorts = 65536 B (self, then neigh)
#define WS_BIAS    3080192      // 128 * 4
#define WS_BSUM    3081216      // blockSum: 256 * 4
#define WS_HB      3084288      // h in bf16: 50000*128*2 = 12.8 MB
// total ~15.9 MB

#define SCAN_NB ((N_NODES + 255) / 256)   // 196 blocks
#define CVT_N   (N_NODES * DIM / 4)       // 1.6M float4-quads

typedef __attribute__((ext_vector_type(8))) short short8;
typedef __attribute__((ext_vector_type(4))) float floatx4;

__device__ __forceinline__ short f2bf(float f) {
    union { float f; uint32_t u; } x; x.f = f;
    uint32_t r = x.u + 0x7fffu + ((x.u >> 16) & 1u);   // round-to-nearest-even
    return (short)(r >> 16);
}
__device__ __forceinline__ float bflo(uint32_t v) {
    union { uint32_t u; float f; } x; x.u = v << 16; return x.f;
}
__device__ __forceinline__ float bfhi(uint32_t v) {
    union { uint32_t u; float f; } x; x.u = v & 0xffff0000u; return x.f;
}
__device__ __forceinline__ uint32_t packbf(float lo, float hi) {
    return (uint32_t)(uint16_t)f2bf(lo) | ((uint32_t)(uint16_t)f2bf(hi) << 16);
}

// ---------------- prep: zero counts, swizzle weights to B-fragment order, bias sum
__global__ void k_prep(const float* __restrict__ Wself,
                       const float* __restrict__ Wneigh,
                       const float* __restrict__ bself,
                       const float* __restrict__ bneigh,
                       int* __restrict__ cnt,
                       short* __restrict__ bfrag,
                       float* __restrict__ biasSum) {
    int id = blockIdx.x * blockDim.x + threadIdx.x;
    if (id < N_NODES) cnt[id] = 0;
    int wid = id - N_NODES;
    if (wid >= 0 && wid < 4096) {
        // fragment layout: ((t*4 + c)*64 + lane)*8 + j  holds  W[c*32 + (lane>>4)*8 + j][t*16 + (lane&15)]
        int w    = wid >> 11;          // 0 = self, 1 = neigh
        int fi   = wid & 2047;
        int lane = fi & 63;
        int tc   = fi >> 6;
        int c    = tc & 3, t = tc >> 2;
        const float* W = w ? Wneigh : Wself;
        int kbase = c * 32 + (lane >> 4) * 8;
        int n     = t * 16 + (lane & 15);
        short* dst = bfrag + (size_t)wid * 8;
        #pragma unroll
        for (int j = 0; j < 8; ++j) dst[j] = f2bf(W[(kbase + j) * DIM + n]);
    }
    int bid = id - N_NODES - 4096;
    if (bid >= 0 && bid < DIM) biasSum[bid] = bself[bid] + bneigh[bid];
}

// ---------------- fused: count in-degree (atomics, latency-bound) + h -> bf16 (BW-bound)
__global__ void k_countcvt(const int* __restrict__ dst, int* __restrict__ cnt,
                           const float4* __restrict__ h4, ushort4* __restrict__ hb4) {
    int id = blockIdx.x * blockDim.x + threadIdx.x;
    if (id < N_EDGES) atomicAdd(&cnt[dst[id]], 1);
    if (id < CVT_N) {
        float4 v = h4[id];
        ushort4 o;
        o.x = (uint16_t)f2bf(v.x); o.y = (uint16_t)f2bf(v.y);
        o.z = (uint16_t)f2bf(v.z); o.w = (uint16_t)f2bf(v.w);
        hb4[id] = o;
    }
}

// ---------------- scan phase A: per-block local exclusive scan + block totals
__global__ __launch_bounds__(256) void k_scanA(const int* __restrict__ cnt,
                                               int* __restrict__ off,
                                               int* __restrict__ blockSum) {
    __shared__ int s[256];
    int t = threadIdx.x;
    int i = blockIdx.x * 256 + t;
    int v = (i < N_NODES) ? cnt[i] : 0;
    s[t] = v;
    __syncthreads();
    int val = v;
    #pragma unroll
    for (int o = 1; o < 256; o <<= 1) {
        int add = (t >= o) ? s[t - o] : 0;
        __syncthreads();
        val += add; s[t] = val;
        __syncthreads();
    }
    if (i < N_NODES) off[i] = val - v;          // local exclusive
    if (t == 255) blockSum[blockIdx.x] = val;   // block total
}

// ---------------- scan phase C: each block redundantly reduces its block-offset
// (replaces the separate middle-scan dispatch; no inter-block sync needed)
__global__ __launch_bounds__(256) void k_scanC(int* __restrict__ off,
                                               int* __restrict__ cur,
                                               const int* __restrict__ blockSum) {
    __shared__ int sOff;
    int b = blockIdx.x;
    int t = threadIdx.x;
    if (t < 64) {
        int s = 0;
        for (int j = t; j < b; j += 64) s += blockSum[j];
        #pragma unroll
        for (int k = 1; k < 64; k <<= 1) s += __shfl_xor(s, k, 64);
        if (t == 0) sOff = s;
    }
    __syncthreads();
    int boff = sOff;
    int i = b * 256 + t;
    if (i < N_NODES) {
        int o = off[i] + boff;
        off[i] = o; cur[i] = o;
    }
    if (b == SCAN_NB - 1 && t == 0) off[N_NODES] = boff + blockSum[b];  // grand total
}

// ---------------- scatter edge sources into CSR slots
__global__ void k_fill(const int* __restrict__ src, const int* __restrict__ dst,
                       int* __restrict__ cur, int* __restrict__ csr) {
    int e = blockIdx.x * blockDim.x + threadIdx.x;
    if (e < N_EDGES) {
        int d = dst[e];
        int p = atomicAdd(&cur[d], 1);
        csr[p] = src[e];
    }
}

// ---------------- fused aggregation + dual GEMM.
// Block = 4 waves, 16 nodes (3125 blocks exactly). Wave w aggregates nodes
// w*4..w*4+3 (quarter-wave = one edge, lane loads uint4 = 8 bf16 cols) into a
// padded LDS tile, then all waves MFMA: out = h@Ws + agg@Wn + bias.
// B-fragments live in 64 VGPRs (coalesced global loads) -> tiny LDS, 4 blocks/CU.
__global__ __launch_bounds__(256, 4) void k_aggemm(
        const uint4* __restrict__ hb4, const short* __restrict__ hb,
        const int* __restrict__ off, const int* __restrict__ csr,
        const short* __restrict__ bfrag, const float* __restrict__ biasSum,
        float* __restrict__ out) {
    __shared__ uint4 aggT[16 * 17];   // 16 rows, stride 17 uint4 (272 B): pad kills bank conflicts
    int w = threadIdx.x >> 6, lane = threadIdx.x & 63;
    int q = lane >> 4;          // quarter
    int c = lane & 15;          // col-group in agg phase; row m in gemm phase
    int row0 = blockIdx.x * 16;

    // ---- B fragments into registers (self + neigh, 4 k-chunks, this wave's 2 col-tiles)
    short8 bS[4][2], bN[4][2];
    #pragma unroll
    for (int c0 = 0; c0 < 4; ++c0) {
        #pragma unroll
        for (int tt = 0; tt < 2; ++tt) {
            int t = w * 2 + tt;
            bS[c0][tt] = *(const short8*)(bfrag + ((size_t)((t * 4 + c0) * 64 + lane)) * 8);
            bN[c0][tt] = *(const short8*)(bfrag + 16384 + ((size_t)((t * 4 + c0) * 64 + lane)) * 8);
        }
    }

    // ---- aggregate this wave's 4 nodes
    #pragma unroll 1
    for (int j = 0; j < 4; ++j) {
        int node = row0 + w * 4 + j;
        int beg = off[node], end = off[node + 1];
        float a0=0.f,a1=0.f,a2=0.f,a3=0.f,a4=0.f,a5=0.f,a6=0.f,a7=0.f;
        for (int e = beg + q; e < end; e += 4) {
            int s = csr[e];
            uint4 v = hb4[(size_t)s * 16 + c];
            a0 += bflo(v.x); a1 += bfhi(v.x);
            a2 += bflo(v.y); a3 += bfhi(v.y);
            a4 += bflo(v.z); a5 += bfhi(v.z);
            a6 += bflo(v.w); a7 += bfhi(v.w);
        }
        a0 += __shfl_xor(a0, 16, 64); a0 += __shfl_xor(a0, 32, 64);
        a1 += __shfl_xor(a1, 16, 64); a1 += __shfl_xor(a1, 32, 64);
        a2 += __shfl_xor(a2, 16, 64); a2 += __shfl_xor(a2, 32, 64);
        a3 += __shfl_xor(a3, 16, 64); a3 += __shfl_xor(a3, 32, 64);
        a4 += __shfl_xor(a4, 16, 64); a4 += __shfl_xor(a4, 32, 64);
        a5 += __shfl_xor(a5, 16, 64); a5 += __shfl_xor(a5, 32, 64);
        a6 += __shfl_xor(a6, 16, 64); a6 += __shfl_xor(a6, 32, 64);
        a7 += __shfl_xor(a7, 16, 64); a7 += __shfl_xor(a7, 32, 64);
        uint4 sv = hb4[(size_t)node * 16 + c];   // self loop
        a0 += bflo(sv.x); a1 += bfhi(sv.x);
        a2 += bflo(sv.y); a3 += bfhi(sv.y);
        a4 += bflo(sv.z); a5 += bfhi(sv.z);
        a6 += bflo(sv.w); a7 += bfhi(sv.w);
        float inv = 1.0f / (float)(end - beg + 1);
        if (q == 0) {
            uint4 o;
            o.x = packbf(a0 * inv, a1 * inv);
            o.y = packbf(a2 * inv, a3 * inv);
            o.z = packbf(a4 * inv, a5 * inv);
            o.w = packbf(a6 * inv, a7 * inv);
            aggT[(w * 4 + j) * 17 + c] = o;
        }
    }
    __syncthreads();

    // ---- dual GEMM on the 16 rows; this wave covers cols [w*32, w*32+32)
    floatx4 acc[2];
    acc[0] = (floatx4){0.f,0.f,0.f,0.f};
    acc[1] = (floatx4){0.f,0.f,0.f,0.f};
    const short* hr = hb + (size_t)(row0 + c) * DIM + q * 8;   // A-frag: row m=c, k=c0*32+q*8
    #pragma unroll
    for (int c0 = 0; c0 < 4; ++c0) {
        short8 ah = *(const short8*)(hr + c0 * 32);
        short8 aa = *(const short8*)(&aggT[c * 17 + c0 * 4 + q]);
        #pragma unroll
        for (int tt = 0; tt < 2; ++tt) {
            acc[tt] = __builtin_amdgcn_mfma_f32_16x16x32_bf16(ah, bS[c0][tt], acc[tt], 0, 0, 0);
            acc[tt] = __builtin_amdgcn_mfma_f32_16x16x32_bf16(aa, bN[c0][tt], acc[tt], 0, 0, 0);
        }
    }
    #pragma unroll
    for (int tt = 0; tt < 2; ++tt) {
        int t = w * 2 + tt;
        float b = biasSum[t * 16 + c];
        #pragma unroll
        for (int r = 0; r < 4; ++r) {
            int row = row0 + q * 4 + r;                      // C/D: row = quad*4 + reg
            out[(size_t)row * DIM + t * 16 + c] = acc[tt][r] + b;   // col = t*16 + m
        }
    }
}

extern "C" void kernel_launch(void* const* d_in, const int* in_sizes, int n_in,
                              void* d_out, int out_size, void* d_ws, size_t ws_size,
                              hipStream_t stream) {
    const float* h      = (const float*)d_in[0];
    const int*   edges  = (const int*)d_in[1];   // [2, 600000] int32
    const float* Wself  = (const float*)d_in[2];
    const float* bself  = (const float*)d_in[3];
    const float* Wneigh = (const float*)d_in[4];
    const float* bneigh = (const float*)d_in[5];
    float* out = (float*)d_out;
    char*  ws  = (char*)d_ws;

    int*      cnt      = (int*)(ws + WS_CNT);
    int*      off      = (int*)(ws + WS_OFF);
    int*      cur      = (int*)(ws + WS_CUR);
    int*      csr      = (int*)(ws + WS_CSR);
    short*    bfrag    = (short*)(ws + WS_BFRAG);
    float*    biasSum  = (float*)(ws + WS_BIAS);
    int*      blockSum = (int*)(ws + WS_BSUM);
    short*    hb       = (short*)(ws + WS_HB);

    const int* esrc = edges;
    const int* edst = edges + N_EDGES;

    int prepN = N_NODES + 4096 + DIM;
    k_prep<<<(prepN + 255) / 256, 256, 0, stream>>>(Wself, Wneigh, bself, bneigh,
                                                    cnt, bfrag, biasSum);
    k_countcvt<<<(CVT_N + 255) / 256, 256, 0, stream>>>(edst, cnt, (const float4*)h,
                                                        (ushort4*)hb);
    k_scanA<<<SCAN_NB, 256, 0, stream>>>(cnt, off, blockSum);
    k_scanC<<<SCAN_NB, 256, 0, stream>>>(off, cur, blockSum);
    k_fill<<<(N_EDGES + 255) / 256, 256, 0, stream>>>(esrc, edst, cur, csr);
    k_aggemm<<<N_NODES / 16, 256, 0, stream>>>((const uint4*)hb, hb, off, csr,
                                               bfrag, biasSum, out);
}

// Round 6
// 185.821 us; speedup vs baseline: 1.1237x; 1.1237x over previous
//
#include <hip/hip_runtime.h>
#include <stdint.h>

#define N_NODES 50000
#define N_EDGES 600000
#define DIM 128

// ---- workspace layout (bytes) ----
#define WS_CNT     0            // 50000 * 4
#define WS_OFF     204800       // 50001 * 4
#define WS_CUR     409600       // 50000 * 4
#define WS_CSR     614400       // 600000 * 4
#define WS_BFRAG   3014656      // 2 * 16384 shorts = 65536 B (self, then neigh)
#define WS_BIAS    3080192      // 128 * 4
#define WS_BSUM    3081216      // blockSum: 256 * 4
#define WS_HB      3084288      // h in bf16: 50000*128*2 = 12.8 MB
#define WS_AGGB    15884288     // agg in bf16: 12.8 MB
// total ~28.7 MB

#define SCAN_NB ((N_NODES + 255) / 256)   // 196 blocks
#define CVT_N   (N_NODES * DIM / 4)       // 1.6M float4-quads

typedef __attribute__((ext_vector_type(8))) short short8;
typedef __attribute__((ext_vector_type(4))) float floatx4;

__device__ __forceinline__ short f2bf(float f) {
    union { float f; uint32_t u; } x; x.f = f;
    uint32_t r = x.u + 0x7fffu + ((x.u >> 16) & 1u);   // round-to-nearest-even
    return (short)(r >> 16);
}
__device__ __forceinline__ float bflo(uint32_t v) {
    union { uint32_t u; float f; } x; x.u = v << 16; return x.f;
}
__device__ __forceinline__ float bfhi(uint32_t v) {
    union { uint32_t u; float f; } x; x.u = v & 0xffff0000u; return x.f;
}
__device__ __forceinline__ uint32_t packbf(float lo, float hi) {
    return (uint32_t)(uint16_t)f2bf(lo) | ((uint32_t)(uint16_t)f2bf(hi) << 16);
}

// ---------------- prep: zero counts, swizzle weights to B-fragment order, bias sum
__global__ void k_prep(const float* __restrict__ Wself,
                       const float* __restrict__ Wneigh,
                       const float* __restrict__ bself,
                       const float* __restrict__ bneigh,
                       int* __restrict__ cnt,
                       short* __restrict__ bfrag,
                       float* __restrict__ biasSum) {
    int id = blockIdx.x * blockDim.x + threadIdx.x;
    if (id < N_NODES) cnt[id] = 0;
    int wid = id - N_NODES;
    if (wid >= 0 && wid < 4096) {
        // fragment layout: ((t*4 + c)*64 + lane)*8 + j  holds  W[c*32 + (lane>>4)*8 + j][t*16 + (lane&15)]
        int w    = wid >> 11;          // 0 = self, 1 = neigh
        int fi   = wid & 2047;
        int lane = fi & 63;
        int tc   = fi >> 6;
        int c    = tc & 3, t = tc >> 2;
        const float* W = w ? Wneigh : Wself;
        int kbase = c * 32 + (lane >> 4) * 8;
        int n     = t * 16 + (lane & 15);
        short* dst = bfrag + (size_t)wid * 8;
        #pragma unroll
        for (int j = 0; j < 8; ++j) dst[j] = f2bf(W[(kbase + j) * DIM + n]);
    }
    int bid = id - N_NODES - 4096;
    if (bid >= 0 && bid < DIM) biasSum[bid] = bself[bid] + bneigh[bid];
}

// ---------------- fused: count in-degree (atomics, latency-bound) + h -> bf16 (BW-bound)
__global__ void k_countcvt(const int* __restrict__ dst, int* __restrict__ cnt,
                           const float4* __restrict__ h4, ushort4* __restrict__ hb4) {
    int id = blockIdx.x * blockDim.x + threadIdx.x;
    if (id < N_EDGES) atomicAdd(&cnt[dst[id]], 1);
    if (id < CVT_N) {
        float4 v = h4[id];
        ushort4 o;
        o.x = (uint16_t)f2bf(v.x); o.y = (uint16_t)f2bf(v.y);
        o.z = (uint16_t)f2bf(v.z); o.w = (uint16_t)f2bf(v.w);
        hb4[id] = o;
    }
}

// ---------------- scan phase A: per-block local exclusive scan + block totals
__global__ __launch_bounds__(256) void k_scanA(const int* __restrict__ cnt,
                                               int* __restrict__ off,
                                               int* __restrict__ blockSum) {
    __shared__ int s[256];
    int t = threadIdx.x;
    int i = blockIdx.x * 256 + t;
    int v = (i < N_NODES) ? cnt[i] : 0;
    s[t] = v;
    __syncthreads();
    int val = v;
    #pragma unroll
    for (int o = 1; o < 256; o <<= 1) {
        int add = (t >= o) ? s[t - o] : 0;
        __syncthreads();
        val += add; s[t] = val;
        __syncthreads();
    }
    if (i < N_NODES) off[i] = val - v;          // local exclusive
    if (t == 255) blockSum[blockIdx.x] = val;   // block total
}

// ---------------- scan phase C: each block redundantly reduces its block-offset
// (no separate middle-scan dispatch; no inter-block sync needed)
__global__ __launch_bounds__(256) void k_scanC(int* __restrict__ off,
                                               int* __restrict__ cur,
                                               const int* __restrict__ blockSum) {
    __shared__ int sOff;
    int b = blockIdx.x;
    int t = threadIdx.x;
    if (t < 64) {
        int s = 0;
        for (int j = t; j < b; j += 64) s += blockSum[j];
        #pragma unroll
        for (int k = 1; k < 64; k <<= 1) s += __shfl_xor(s, k, 64);
        if (t == 0) sOff = s;
    }
    __syncthreads();
    int boff = sOff;
    int i = b * 256 + t;
    if (i < N_NODES) {
        int o = off[i] + boff;
        off[i] = o; cur[i] = o;
    }
    if (b == SCAN_NB - 1 && t == 0) off[N_NODES] = boff + blockSum[b];  // grand total
}

// ---------------- scatter edge sources into CSR slots
__global__ void k_fill(const int* __restrict__ src, const int* __restrict__ dst,
                       int* __restrict__ cur, int* __restrict__ csr) {
    int e = blockIdx.x * blockDim.x + threadIdx.x;
    if (e < N_EDGES) {
        int d = dst[e];
        int p = atomicAdd(&cur[d], 1);
        csr[p] = src[e];
    }
}

// ---------------- mean aggregation: ONE WAVE PER NODE (max MLP), quarter-wave = one
// edge, lane loads uint4 (16B = 8 bf16 cols); edge loop unrolled x2 -> two
// independent gather chains in flight per lane.
__global__ void k_agg(const uint4* __restrict__ hb4, const int* __restrict__ off,
                      const int* __restrict__ csr, uint4* __restrict__ aggb4) {
    int gt   = blockIdx.x * blockDim.x + threadIdx.x;
    int node = gt >> 6;
    if (node >= N_NODES) return;
    int lane = threadIdx.x & 63;
    int q = lane >> 4;          // quarter: which edge in the group of 4
    int c = lane & 15;          // col group: 8 bf16 cols = one uint4 (row = 16 uint4)
    int beg = off[node], end = off[node + 1];

    float a0=0.f,a1=0.f,a2=0.f,a3=0.f,a4=0.f,a5=0.f,a6=0.f,a7=0.f;   // chain A
    float b0=0.f,b1=0.f,b2=0.f,b3=0.f,b4=0.f,b5=0.f,b6=0.f,b7=0.f;   // chain B
    int e = beg + q;
    for (; e + 4 < end; e += 8) {
        int s0 = csr[e];
        int s1 = csr[e + 4];
        uint4 v0 = hb4[(size_t)s0 * 16 + c];
        uint4 v1 = hb4[(size_t)s1 * 16 + c];
        a0 += bflo(v0.x); a1 += bfhi(v0.x);
        a2 += bflo(v0.y); a3 += bfhi(v0.y);
        a4 += bflo(v0.z); a5 += bfhi(v0.z);
        a6 += bflo(v0.w); a7 += bfhi(v0.w);
        b0 += bflo(v1.x); b1 += bfhi(v1.x);
        b2 += bflo(v1.y); b3 += bfhi(v1.y);
        b4 += bflo(v1.z); b5 += bfhi(v1.z);
        b6 += bflo(v1.w); b7 += bfhi(v1.w);
    }
    if (e < end) {
        uint4 v = hb4[(size_t)csr[e] * 16 + c];
        a0 += bflo(v.x); a1 += bfhi(v.x);
        a2 += bflo(v.y); a3 += bfhi(v.y);
        a4 += bflo(v.z); a5 += bfhi(v.z);
        a6 += bflo(v.w); a7 += bfhi(v.w);
    }
    a0 += b0; a1 += b1; a2 += b2; a3 += b3;
    a4 += b4; a5 += b5; a6 += b6; a7 += b7;
    // combine the 4 quarter-wave partials (lanes c, c+16, c+32, c+48 hold same cols)
    a0 += __shfl_xor(a0, 16, 64); a0 += __shfl_xor(a0, 32, 64);
    a1 += __shfl_xor(a1, 16, 64); a1 += __shfl_xor(a1, 32, 64);
    a2 += __shfl_xor(a2, 16, 64); a2 += __shfl_xor(a2, 32, 64);
    a3 += __shfl_xor(a3, 16, 64); a3 += __shfl_xor(a3, 32, 64);
    a4 += __shfl_xor(a4, 16, 64); a4 += __shfl_xor(a4, 32, 64);
    a5 += __shfl_xor(a5, 16, 64); a5 += __shfl_xor(a5, 32, 64);
    a6 += __shfl_xor(a6, 16, 64); a6 += __shfl_xor(a6, 32, 64);
    a7 += __shfl_xor(a7, 16, 64); a7 += __shfl_xor(a7, 32, 64);
    // self loop (same value added on all lanes -> stays quarter-consistent)
    uint4 sv = hb4[(size_t)node * 16 + c];
    a0 += bflo(sv.x); a1 += bfhi(sv.x);
    a2 += bflo(sv.y); a3 += bfhi(sv.y);
    a4 += bflo(sv.z); a5 += bfhi(sv.z);
    a6 += bflo(sv.w); a7 += bfhi(sv.w);
    float inv = 1.0f / (float)(end - beg + 1);
    if (q == 0) {
        uint4 o;
        o.x = packbf(a0 * inv, a1 * inv);
        o.y = packbf(a2 * inv, a3 * inv);
        o.z = packbf(a4 * inv, a5 * inv);
        o.w = packbf(a6 * inv, a7 * inv);
        aggb4[(size_t)node * 16 + c] = o;
    }
}

// ---------------- fused dual GEMM: out = h@Ws + agg@Wn + (bs+bn), bf16 MFMA
__global__ __launch_bounds__(256) void k_gemm(const short* __restrict__ hb,
                                              const short* __restrict__ aggb,
                                              const short* __restrict__ bfrag,
                                              const float* __restrict__ biasSum,
                                              float* __restrict__ out) {
    __shared__ short lds[32768];   // 64 KB: self frags [0..16384), neigh [16384..32768)
    {
        const int4* g = (const int4*)bfrag;
        int4* l = (int4*)lds;
        #pragma unroll
        for (int i = 0; i < 16; ++i) l[threadIdx.x + 256 * i] = g[threadIdx.x + 256 * i];
    }
    __syncthreads();
    int wave = threadIdx.x >> 6, lane = threadIdx.x & 63;
    int row0 = blockIdx.x * 64 + wave * 16;
    if (row0 >= N_NODES) return;
    int m = lane & 15, q = lane >> 4;
    const short* hr = hb   + (row0 + m) * DIM + q * 8;
    const short* ar = aggb + (row0 + m) * DIM + q * 8;
    floatx4 acc[8];
    #pragma unroll
    for (int t = 0; t < 8; ++t) acc[t] = (floatx4){0.f, 0.f, 0.f, 0.f};
    const short* ldsS = lds;
    const short* ldsN = lds + 16384;
    #pragma unroll
    for (int c = 0; c < 4; ++c) {
        short8 ah = *(const short8*)(hr + c * 32);
        short8 aa = *(const short8*)(ar + c * 32);
        #pragma unroll
        for (int t = 0; t < 8; ++t) {
            short8 bs = *(const short8*)(ldsS + ((t * 4 + c) * 64 + lane) * 8);
            short8 bn = *(const short8*)(ldsN + ((t * 4 + c) * 64 + lane) * 8);
            acc[t] = __builtin_amdgcn_mfma_f32_16x16x32_bf16(ah, bs, acc[t], 0, 0, 0);
            acc[t] = __builtin_amdgcn_mfma_f32_16x16x32_bf16(aa, bn, acc[t], 0, 0, 0);
        }
    }
    #pragma unroll
    for (int t = 0; t < 8; ++t) {
        float b = biasSum[t * 16 + m];
        #pragma unroll
        for (int r = 0; r < 4; ++r) {
            int row = row0 + q * 4 + r;           // C/D: row = quad*4 + reg
            out[row * DIM + t * 16 + m] = acc[t][r] + b;   // col = t*16 + (lane&15)
        }
    }
}

extern "C" void kernel_launch(void* const* d_in, const int* in_sizes, int n_in,
                              void* d_out, int out_size, void* d_ws, size_t ws_size,
                              hipStream_t stream) {
    const float* h      = (const float*)d_in[0];
    const int*   edges  = (const int*)d_in[1];   // [2, 600000] int32
    const float* Wself  = (const float*)d_in[2];
    const float* bself  = (const float*)d_in[3];
    const float* Wneigh = (const float*)d_in[4];
    const float* bneigh = (const float*)d_in[5];
    float* out = (float*)d_out;
    char*  ws  = (char*)d_ws;

    int*      cnt      = (int*)(ws + WS_CNT);
    int*      off      = (int*)(ws + WS_OFF);
    int*      cur      = (int*)(ws + WS_CUR);
    int*      csr      = (int*)(ws + WS_CSR);
    short*    bfrag    = (short*)(ws + WS_BFRAG);
    float*    biasSum  = (float*)(ws + WS_BIAS);
    int*      blockSum = (int*)(ws + WS_BSUM);
    short*    hb       = (short*)(ws + WS_HB);
    short*    aggb     = (short*)(ws + WS_AGGB);

    const int* esrc = edges;
    const int* edst = edges + N_EDGES;

    int prepN = N_NODES + 4096 + DIM;
    k_prep<<<(prepN + 255) / 256, 256, 0, stream>>>(Wself, Wneigh, bself, bneigh,
                                                    cnt, bfrag, biasSum);
    k_countcvt<<<(CVT_N + 255) / 256, 256, 0, stream>>>(edst, cnt, (const float4*)h,
                                                        (ushort4*)hb);
    k_scanA<<<SCAN_NB, 256, 0, stream>>>(cnt, off, blockSum);
    k_scanC<<<SCAN_NB, 256, 0, stream>>>(off, cur, blockSum);
    k_fill<<<(N_EDGES + 255) / 256, 256, 0, stream>>>(esrc, edst, cur, csr);
    k_agg<<<(N_NODES * 64 + 255) / 256, 256, 0, stream>>>((const uint4*)hb, off, csr,
                                                          (uint4*)aggb);
    k_gemm<<<(N_NODES + 63) / 64, 256, 0, stream>>>(hb, aggb, bfrag, biasSum, out);
}